// Round 1
// baseline (5212.811 us; speedup 1.0000x reference)
//
#include <hip/hip_runtime.h>
#include <stdint.h>

#define B_ 64
#define T_ 2048
#define F_ 128
#define H_ 256
#define TC_ 1022

typedef __bf16 bf16x8 __attribute__((ext_vector_type(8)));
typedef float f32x4 __attribute__((ext_vector_type(4)));
typedef unsigned long long u64;

__device__ __forceinline__ ushort f2bf(float f) {
    uint32_t u = __builtin_bit_cast(uint32_t, f);
    u += 0x7FFFu + ((u >> 16) & 1u);
    return (ushort)(u >> 16);
}
__device__ __forceinline__ float sigmoidf_(float x) { return 1.f / (1.f + __expf(-x)); }
__device__ __forceinline__ float tanhf_(float x) {
    x = fminf(15.f, fmaxf(-15.f, x));
    float e = __expf(2.f * x);
    return (e - 1.f) / (e + 1.f);
}

// ---- Kernel 1: sum of squares over T for F.normalize(dim=1) ----
__global__ __launch_bounds__(128) void k_sqsum(const float* __restrict__ in,
                                               float* __restrict__ sq) {
    int b = blockIdx.x >> 4, tq = blockIdx.x & 15, f = threadIdx.x;
    const float* p = in + ((size_t)b * T_ + (size_t)tq * 128) * F_ + f;
    float acc = 0.f;
#pragma unroll 8
    for (int t = 0; t < 128; ++t) { float v = p[(size_t)t * F_]; acc += v * v; }
    atomicAdd(&sq[b * F_ + f], acc);
}

// ---- Kernel 2: weight repack to bf16 block-row order; bias combine ----
// wbf[g2][m][k]: g2 = unit>>2 (0..63), m = uu*4+gate, k: [0,64)=w_ih, [64,320)=w_hh
__global__ __launch_bounds__(256) void k_prep(const float* __restrict__ wih, const float* __restrict__ whh,
                                              const float* __restrict__ bih, const float* __restrict__ bhh,
                                              ushort* __restrict__ wbf, float* __restrict__ bias) {
    int e = blockIdx.x * 256 + threadIdx.x;
    if (e < 64 * 16 * 320) {
        int g = e / 5120, m = (e / 320) & 15, k = e % 320;
        int j = (m & 3) * 256 + g * 4 + (m >> 2);  // gate*256 + unit
        float v = (k < 64) ? wih[j * 64 + k] : whh[j * 256 + (k - 64)];
        wbf[e] = f2bf(v);
    }
    if (e < 1024) bias[e] = bih[e] + bhh[e];
}

// ---- Kernel 3: fused normalize + conv1d(K=5,S=2) + bias + relu -> li bf16 [tc][b][72pad] ----
__global__ __launch_bounds__(256) void k_conv(const float* __restrict__ in, const float* __restrict__ cw,
                                              const float* __restrict__ cb, const float* __restrict__ sq,
                                              ushort* __restrict__ li) {
    __shared__ float rn[128];
    __shared__ __align__(16) float xs[67 * 129];
    __shared__ __align__(16) float wl[80 * 68];
    int b = blockIdx.x >> 5, tile = blockIdx.x & 31;
    int tc0 = tile * 32;
    int tid = threadIdx.x;
    if (tid < 128) { float ss = sq[b * 128 + tid]; rn[tid] = 1.f / fmaxf(sqrtf(ss), 1e-12f); }
    __syncthreads();
    const float* ip = in + ((size_t)b * T_ + (size_t)(2 * tc0)) * F_;
    for (int i = tid; i < 67 * 128; i += 256) {
        int r = i >> 7, f = i & 127;
        int t = 2 * tc0 + r;
        xs[r * 129 + f] = (t < T_) ? ip[(size_t)r * F_ + f] * rn[f] : 0.f;
    }
    int cg = tid & 15, tcg = tid >> 4;
    float a00 = 0, a01 = 0, a10 = 0, a11 = 0, a20 = 0, a21 = 0, a30 = 0, a31 = 0;
    for (int fc = 0; fc < 8; ++fc) {
        __syncthreads();
        for (int i = tid; i < 64 * 80; i += 256) {
            int c = i / 80, j = i - c * 80;
            wl[j * 68 + c] = cw[c * 640 + fc * 80 + j];
        }
        __syncthreads();
#pragma unroll
        for (int fi = 0; fi < 16; ++fi) {
#pragma unroll
            for (int k = 0; k < 5; ++k) {
                const float4 w4 = *(const float4*)&wl[(fi * 5 + k) * 68 + cg * 4];
                float x0 = xs[(4 * tcg + k) * 129 + fc * 16 + fi];
                float x1 = xs[(4 * tcg + 2 + k) * 129 + fc * 16 + fi];
                a00 += w4.x * x0; a01 += w4.x * x1;
                a10 += w4.y * x0; a11 += w4.y * x1;
                a20 += w4.z * x0; a21 += w4.z * x1;
                a30 += w4.w * x0; a31 += w4.w * x1;
            }
        }
    }
    float bc0 = cb[cg * 4 + 0], bc1 = cb[cg * 4 + 1], bc2 = cb[cg * 4 + 2], bc3 = cb[cg * 4 + 3];
#pragma unroll
    for (int tt = 0; tt < 2; ++tt) {
        int tc = tc0 + tcg * 2 + tt;
        if (tc < TC_) {
            float v0 = fmaxf((tt ? a01 : a00) + bc0, 0.f);
            float v1 = fmaxf((tt ? a11 : a10) + bc1, 0.f);
            float v2 = fmaxf((tt ? a21 : a20) + bc2, 0.f);
            float v3 = fmaxf((tt ? a31 : a30) + bc3, 0.f);
            uint2 pk;
            pk.x = (uint32_t)f2bf(v0) | ((uint32_t)f2bf(v1) << 16);
            pk.y = (uint32_t)f2bf(v2) | ((uint32_t)f2bf(v3) << 16);
            *reinterpret_cast<uint2*>(&li[((size_t)tc * 64 + b) * 72 + cg * 4]) = pk;
        }
    }
}

// ---- Kernel 4: pod-structured LSTM scan with DUAL-GROUP latency hiding.
// 16 blocks x 256 thr = 2 PODS of 8 blocks. Pod p owns batches [32p,32p+32) as TWO
// independent 16-batch recurrence groups g=0,1 (batch rows are independent). Within a pod,
// block bq owns units [32bq, 32bq+32) (8 gate-row tiles; wave w holds 2 stationary
// A-fragment tiles, weights SHARED between groups -> 80 VGPR once).
// Each round interleaves the two groups' phases: while group A's h(t) transits the MALL
// (agent-scope fire-and-forget tagged stores, exactly the R6-proven primitive), the block
// computes group B's step t. By the time phase A of round t+1 starts, >1000 cycles have
// elapsed -> first-try poll hit. Exchange latency leaves the critical path entirely.
//   cell u64 = (h[2c]|t<<16) | ((h[2c+1]|t<<16)<<32); image = [b:16][c:128] = 2048 cells.
//   hbuf layout: [(t&1)][pod:2][group:2][2048] = 8 images x 16KB = 128KB (fits old region).
// WAR: per-group parity double-buffer + chain argument (publishing (g,t+2) requires having
// polled all siblings' (g,t+1) tags, which implies every sibling consumed (g,t)). Skew <= 1.
__global__ __launch_bounds__(256) void k_scan(const ushort* __restrict__ li,
                                              const ushort* __restrict__ wbf,
                                              const float* __restrict__ bias,
                                              u64* __restrict__ hbuf,
                                              float* __restrict__ hfin) {
    __shared__ __align__(16) ushort Hs[16 * 264];  // h [b:16][256+8 pad] bf16, rows 528B
    int p = blockIdx.x >> 3, bq = blockIdx.x & 7;
    int tid = threadIdx.x;
    int lane = tid & 63, wave = tid >> 6, l16 = lane & 15, quad = lane >> 4;
    int g2a = bq * 8 + 2 * wave, g2b = g2a + 1;
    int u0 = g2a * 4 + quad, u1 = g2b * 4 + quad;
    // Stationary A-fragments: two 16-row tiles (rows = l16 within each tile). Shared by groups.
    bf16x8 af0[10], af1[10];
    const ushort* wp0 = wbf + ((size_t)(g2a * 16 + l16)) * 320 + quad * 8;
    const ushort* wp1 = wbf + ((size_t)(g2b * 16 + l16)) * 320 + quad * 8;
#pragma unroll
    for (int s = 0; s < 10; ++s) { af0[s] = *(const bf16x8*)(wp0 + s * 32);
                                   af1[s] = *(const bf16x8*)(wp1 + s * 32); }
    float bi0 = bias[u0], bf0 = bias[256 + u0], bg0 = bias[512 + u0], bo0 = bias[768 + u0];
    float bi1 = bias[u1], bf1 = bias[256 + u1], bg1 = bias[512 + u1], bo1 = bias[768 + u1];
    float cs[2][2] = {{0.f, 0.f}, {0.f, 0.f}};  // [group][tile], indices literal after unroll
    // xt preload for t=0, both groups (B-frags shared by both M-tiles)
    bf16x8 xl0[2], xl1[2];
#pragma unroll
    for (int g = 0; g < 2; ++g) {
        const ushort* xpp = li + ((size_t)(32 * p + 16 * g + l16)) * 72 + quad * 8;
        xl0[g] = *(const bf16x8*)xpp;
        xl1[g] = *(const bf16x8*)(xpp + 32);
    }
#pragma unroll 1
    for (int t = 0; t < TC_; ++t) {
#pragma unroll
        for (int g = 0; g < 2; ++g) {
            // First-try poll loads issued BEFORE the x-MFMAs (hide load latency under issue).
            const u64* src = hbuf + ((((size_t)((t - 1) & 1)) * 4 + p * 2 + g) << 11) + tid * 8;
            u64 vv[8];
            if (t > 0) {
#pragma unroll
                for (int k = 0; k < 8; ++k)
                    vv[k] = __hip_atomic_load(src + k, __ATOMIC_RELAXED, __HIP_MEMORY_SCOPE_AGENT);
            }
            f32x4 A0 = {0.f, 0.f, 0.f, 0.f}, A1 = {0.f, 0.f, 0.f, 0.f};
            // x-part MFMAs (xt already in regs from prefetch).
            A0 = __builtin_amdgcn_mfma_f32_16x16x32_bf16(af0[0], xl0[g], A0, 0, 0, 0);
            A1 = __builtin_amdgcn_mfma_f32_16x16x32_bf16(af1[0], xl0[g], A1, 0, 0, 0);
            A0 = __builtin_amdgcn_mfma_f32_16x16x32_bf16(af0[1], xl1[g], A0, 0, 0, 0);
            A1 = __builtin_amdgcn_mfma_f32_16x16x32_bf16(af1[1], xl1[g], A1, 0, 0, 0);
            if (t > 0) {
                uint tg = (uint)(t - 1);
                uint m = 0;
#pragma unroll
                for (int k = 0; k < 8; ++k)
                    m |= (((uint)(vv[k] >> 16) & 0xFFFFu) ^ tg) | (((uint)(vv[k] >> 48)) ^ tg);
                bool ok = (m == 0);
                int guard = 0;
                while (!__all(ok) && ++guard < (1 << 14)) {
#pragma unroll
                    for (int k = 0; k < 8; ++k)
                        vv[k] = __hip_atomic_load(src + k, __ATOMIC_RELAXED, __HIP_MEMORY_SCOPE_AGENT);
                    m = 0;
#pragma unroll
                    for (int k = 0; k < 8; ++k)
                        m |= (((uint)(vv[k] >> 16) & 0xFFFFu) ^ tg) | (((uint)(vv[k] >> 48)) ^ tg);
                    ok = (m == 0);
                }
                // Stage pod-group image to LDS: thread owns cells [8*tid, 8*tid+8) ->
                // b = tid>>4, c0 = (tid&15)*8; cell c = units {2c,2c+1} -> 16 contiguous ushorts.
                {
                    int b = tid >> 4, c0 = (tid & 15) * 8;
                    uint w[8];
#pragma unroll
                    for (int k = 0; k < 8; ++k)
                        w[k] = ((uint)vv[k] & 0xFFFFu) | (((uint)(vv[k] >> 32) & 0xFFFFu) << 16);
                    uint4 wa, wb;
                    wa.x = w[0]; wa.y = w[1]; wa.z = w[2]; wa.w = w[3];
                    wb.x = w[4]; wb.y = w[5]; wb.z = w[6]; wb.w = w[7];
                    *(uint4*)((char*)Hs + b * 528 + c0 * 4) = wa;
                    *(uint4*)((char*)Hs + b * 528 + c0 * 4 + 16) = wb;
                }
                __syncthreads();
                // h-part MFMAs: frag = Hs[row=l16][units s*32+quad*8 ..+8], shared by both tiles.
#pragma unroll
                for (int s = 0; s < 8; ++s) {
                    bf16x8 bh = *(const bf16x8*)((const char*)Hs + l16 * 528 + s * 64 + quad * 16);
                    A0 = __builtin_amdgcn_mfma_f32_16x16x32_bf16(af0[2 + s], bh, A0, 0, 0, 0);
                    A1 = __builtin_amdgcn_mfma_f32_16x16x32_bf16(af1[2 + s], bh, A1, 0, 0, 0);
                }
                __syncthreads();  // frag reads done before next phase's staging overwrites Hs
            }
            // Epilogue: lane owns (u0,bb) and (u1,bb) for this group.
            int bb = 32 * p + 16 * g + l16;
            float hv0, hv1;
            {
                float gi = A0[0] + bi0, gf = A0[1] + bf0, gg = A0[2] + bg0, go = A0[3] + bo0;
                float ii = sigmoidf_(gi), ff = sigmoidf_(gf), g2 = tanhf_(gg), oo = sigmoidf_(go);
                cs[g][0] = ff * cs[g][0] + ii * g2;
                hv0 = oo * tanhf_(cs[g][0]);
            }
            {
                float gi = A1[0] + bi1, gf = A1[1] + bf1, gg = A1[2] + bg1, go = A1[3] + bo1;
                float ii = sigmoidf_(gi), ff = sigmoidf_(gf), g2 = tanhf_(gg), oo = sigmoidf_(go);
                cs[g][1] = ff * cs[g][1] + ii * g2;
                hv1 = oo * tanhf_(cs[g][1]);
            }
            if (t == TC_ - 1) {
                hfin[u0 * 64 + bb] = hv0;
                hfin[u1 * 64 + bb] = hv1;
            } else {
                // Publish: pack unit pairs via shfl (quad gets quad+1's value, same l16).
                ushort h0 = f2bf(hv0), h1 = f2bf(hv1);
                uint pr0 = ((uint)h0 & 0xFFFFu) | ((uint)__shfl((int)h0, (lane + 16) & 63) << 16);
                uint pr1 = ((uint)h1 & 0xFFFFu) | ((uint)__shfl((int)h1, (lane + 16) & 63) << 16);
                if ((quad & 1) == 0) {
                    uint tg2 = ((uint)t) << 16;
                    u64 w0 = (u64)((pr0 & 0xFFFFu) | tg2) | ((u64)((pr0 >> 16) | tg2) << 32);
                    u64 w1 = (u64)((pr1 & 0xFFFFu) | tg2) | ((u64)((pr1 >> 16) | tg2) << 32);
                    int pc = 16 * bq + 4 * wave + (quad >> 1);  // tile0 pair cell; tile1 = +2
                    u64* dst = hbuf + ((((size_t)(t & 1)) * 4 + p * 2 + g) << 11) + l16 * 128;
                    __hip_atomic_store(dst + pc, w0, __ATOMIC_RELAXED, __HIP_MEMORY_SCOPE_AGENT);
                    __hip_atomic_store(dst + pc + 2, w1, __ATOMIC_RELAXED, __HIP_MEMORY_SCOPE_AGENT);
                }
            }
            // Prefetch next xt for this group (fires now; lands during the other group's phase).
            int tn = (t + 1 < TC_) ? t + 1 : t;
            const ushort* xpn = li + ((size_t)tn * 64 + bb) * 72 + quad * 8;
            xl0[g] = *(const bf16x8*)xpn;
            xl1[g] = *(const bf16x8*)(xpn + 32);
        }
    }
}

// ---- Kernel 5: out[b][o] = h_final[:,b] . lin_w[o,:] + lin_b[o] ----
__global__ __launch_bounds__(64) void k_fin(const float* __restrict__ hfin, const float* __restrict__ lw,
                                            const float* __restrict__ lb, float* __restrict__ out) {
    int o = blockIdx.x, b = threadIdx.x;
    float acc = lb[o];
    const float* wp = lw + o * 256;
#pragma unroll 4
    for (int u2 = 0; u2 < 256; ++u2) acc += hfin[u2 * 64 + b] * wp[u2];
    out[b * 10 + o] = acc;
}

extern "C" void kernel_launch(void* const* d_in, const int* in_sizes, int n_in,
                              void* d_out, int out_size, void* d_ws, size_t ws_size,
                              hipStream_t stream) {
    const float* in  = (const float*)d_in[0];
    // d_in[1] ("r") unused
    const float* cw  = (const float*)d_in[2];
    const float* cb  = (const float*)d_in[3];
    const float* wih = (const float*)d_in[4];
    const float* whh = (const float*)d_in[5];
    const float* bih = (const float*)d_in[6];
    const float* bhh = (const float*)d_in[7];
    const float* lw  = (const float*)d_in[8];
    const float* lb  = (const float*)d_in[9];
    float* out = (float*)d_out;

    char* ws = (char*)d_ws;
    float*  sq   = (float*)(ws + 0);          // 32768 B
    u64*    hbuf = (u64*)(ws + 32768);        // 131072 B: 2 parity x 2 pods x 2 groups x 2048 cells x 8B
    float*  bias = (float*)(ws + 163840);     // 4096 B
    float*  hfin = (float*)(ws + 167936);     // 65536 B  [u][b] fp32
    ushort* wbf  = (ushort*)(ws + 233472);    // 655360 B [g2][16][320] bf16
    ushort* li   = (ushort*)(ws + 888832);    // 9418752 B [tc][b][72] bf16

    hipMemsetAsync(sq, 0, 32768, stream);
    hipMemsetAsync(hbuf, 0xFF, 131072, stream);  // tag fields -> 0xFFFF, never a valid step

    k_sqsum<<<1024, 128, 0, stream>>>(in, sq);
    k_prep<<<1280, 256, 0, stream>>>(wih, whh, bih, bhh, wbf, bias);
    k_conv<<<2048, 256, 0, stream>>>(in, cw, cb, sq, li);
    k_scan<<<16, 256, 0, stream>>>(li, wbf, bias, hbuf, hfin);
    k_fin<<<10, 64, 0, stream>>>(hfin, lw, lb, out);
}

// Round 2
// 2938.209 us; speedup vs baseline: 1.7741x; 1.7741x over previous
//
#include <hip/hip_runtime.h>
#include <stdint.h>

#define B_ 64
#define T_ 2048
#define F_ 128
#define H_ 256
#define TC_ 1022

typedef __bf16 bf16x8 __attribute__((ext_vector_type(8)));
typedef float f32x4 __attribute__((ext_vector_type(4)));
typedef unsigned long long u64;

__device__ __forceinline__ ushort f2bf(float f) {
    uint32_t u = __builtin_bit_cast(uint32_t, f);
    u += 0x7FFFu + ((u >> 16) & 1u);
    return (ushort)(u >> 16);
}
__device__ __forceinline__ float sigmoidf_(float x) { return 1.f / (1.f + __expf(-x)); }
__device__ __forceinline__ float tanhf_(float x) {
    x = fminf(15.f, fmaxf(-15.f, x));
    float e = __expf(2.f * x);
    return (e - 1.f) / (e + 1.f);
}

// ---- Kernel 1: sum of squares over T for F.normalize(dim=1) ----
__global__ __launch_bounds__(128) void k_sqsum(const float* __restrict__ in,
                                               float* __restrict__ sq) {
    int b = blockIdx.x >> 4, tq = blockIdx.x & 15, f = threadIdx.x;
    const float* p = in + ((size_t)b * T_ + (size_t)tq * 128) * F_ + f;
    float acc = 0.f;
#pragma unroll 8
    for (int t = 0; t < 128; ++t) { float v = p[(size_t)t * F_]; acc += v * v; }
    atomicAdd(&sq[b * F_ + f], acc);
}

// ---- Kernel 2: weight repack to bf16 block-row order; bias combine ----
// wbf[g2][m][k]: g2 = unit>>2 (0..63), m = uu*4+gate, k: [0,64)=w_ih, [64,320)=w_hh
__global__ __launch_bounds__(256) void k_prep(const float* __restrict__ wih, const float* __restrict__ whh,
                                              const float* __restrict__ bih, const float* __restrict__ bhh,
                                              ushort* __restrict__ wbf, float* __restrict__ bias) {
    int e = blockIdx.x * 256 + threadIdx.x;
    if (e < 64 * 16 * 320) {
        int g = e / 5120, m = (e / 320) & 15, k = e % 320;
        int j = (m & 3) * 256 + g * 4 + (m >> 2);  // gate*256 + unit
        float v = (k < 64) ? wih[j * 64 + k] : whh[j * 256 + (k - 64)];
        wbf[e] = f2bf(v);
    }
    if (e < 1024) bias[e] = bih[e] + bhh[e];
}

// ---- Kernel 3: fused normalize + conv1d(K=5,S=2) + bias + relu -> li bf16 [tc][b][72pad] ----
__global__ __launch_bounds__(256) void k_conv(const float* __restrict__ in, const float* __restrict__ cw,
                                              const float* __restrict__ cb, const float* __restrict__ sq,
                                              ushort* __restrict__ li) {
    __shared__ float rn[128];
    __shared__ __align__(16) float xs[67 * 129];
    __shared__ __align__(16) float wl[80 * 68];
    int b = blockIdx.x >> 5, tile = blockIdx.x & 31;
    int tc0 = tile * 32;
    int tid = threadIdx.x;
    if (tid < 128) { float ss = sq[b * 128 + tid]; rn[tid] = 1.f / fmaxf(sqrtf(ss), 1e-12f); }
    __syncthreads();
    const float* ip = in + ((size_t)b * T_ + (size_t)(2 * tc0)) * F_;
    for (int i = tid; i < 67 * 128; i += 256) {
        int r = i >> 7, f = i & 127;
        int t = 2 * tc0 + r;
        xs[r * 129 + f] = (t < T_) ? ip[(size_t)r * F_ + f] * rn[f] : 0.f;
    }
    int cg = tid & 15, tcg = tid >> 4;
    float a00 = 0, a01 = 0, a10 = 0, a11 = 0, a20 = 0, a21 = 0, a30 = 0, a31 = 0;
    for (int fc = 0; fc < 8; ++fc) {
        __syncthreads();
        for (int i = tid; i < 64 * 80; i += 256) {
            int c = i / 80, j = i - c * 80;
            wl[j * 68 + c] = cw[c * 640 + fc * 80 + j];
        }
        __syncthreads();
#pragma unroll
        for (int fi = 0; fi < 16; ++fi) {
#pragma unroll
            for (int k = 0; k < 5; ++k) {
                const float4 w4 = *(const float4*)&wl[(fi * 5 + k) * 68 + cg * 4];
                float x0 = xs[(4 * tcg + k) * 129 + fc * 16 + fi];
                float x1 = xs[(4 * tcg + 2 + k) * 129 + fc * 16 + fi];
                a00 += w4.x * x0; a01 += w4.x * x1;
                a10 += w4.y * x0; a11 += w4.y * x1;
                a20 += w4.z * x0; a21 += w4.z * x1;
                a30 += w4.w * x0; a31 += w4.w * x1;
            }
        }
    }
    float bc0 = cb[cg * 4 + 0], bc1 = cb[cg * 4 + 1], bc2 = cb[cg * 4 + 2], bc3 = cb[cg * 4 + 3];
#pragma unroll
    for (int tt = 0; tt < 2; ++tt) {
        int tc = tc0 + tcg * 2 + tt;
        if (tc < TC_) {
            float v0 = fmaxf((tt ? a01 : a00) + bc0, 0.f);
            float v1 = fmaxf((tt ? a11 : a10) + bc1, 0.f);
            float v2 = fmaxf((tt ? a21 : a20) + bc2, 0.f);
            float v3 = fmaxf((tt ? a31 : a30) + bc3, 0.f);
            uint2 pk;
            pk.x = (uint32_t)f2bf(v0) | ((uint32_t)f2bf(v1) << 16);
            pk.y = (uint32_t)f2bf(v2) | ((uint32_t)f2bf(v3) << 16);
            *reinterpret_cast<uint2*>(&li[((size_t)tc * 64 + b) * 72 + cg * 4]) = pk;
        }
    }
}

// ---- Kernel 4: pod-structured LSTM scan (R0-proven 4x4 topology) with EXPLICIT
// CACHE-BYPASS exchange. 16 blocks x 512 thr = 4 PODS of 4 blocks; pod p owns batches
// [16p,16p+16), block q owns units [64q,64q+64); wave w computes two M-tiles, weights
// stationary in regs.
// R1 post-mortem: agent-scope __hip_atomic_ exchange was being served by the
// NON-COHERENT per-XCD L2s — consumers spun ~25-30 fast (~150cy) retries on STALE lines,
// visibility only via incidental eviction (~4500-5500cy). Fix: inline-asm
// global_load/store_dwordx2 with sc0 sc1 (bypass L1+L2, direct MALL), s_waitcnt inside
// the asm block so the compiler cannot schedule the tag check before data lands.
// Tag protocol unchanged: cell u64 = (h[2c]|t<<16)|((h[2c+1]|t<<16)<<32), parity
// double-buffer, chain argument bounds skew <= 1.
// End-of-kernel POISON pass: rewrite own cells' tags to 0xFFFF in BOTH parities via the
// same bypass path, so a later graph iteration's bypass loads can never see this
// iteration's matching tags even if the SDMA memset's visibility differs from L2's.
__global__ __launch_bounds__(512) void k_scan(const ushort* __restrict__ li,
                                              const ushort* __restrict__ wbf,
                                              const float* __restrict__ bias,
                                              u64* __restrict__ hbuf,
                                              float* __restrict__ hfin) {
    __shared__ __align__(16) ushort Hs[16 * 264];  // h [b:16][256+8 pad] bf16, rows 528B
    int p = blockIdx.x >> 2, q = blockIdx.x & 3;
    int tid = threadIdx.x;
    int lane = tid & 63, wave = tid >> 6, l16 = lane & 15, quad = lane >> 4;
    int bb = p * 16 + l16;                    // global batch
    int g2a = q * 16 + 2 * wave, g2b = g2a + 1;
    int u0 = g2a * 4 + quad, u1 = g2b * 4 + quad;
    // Stationary A-fragments: two 16-row tiles (rows = l16 within each tile).
    bf16x8 af0[10], af1[10];
    const ushort* wp0 = wbf + ((size_t)(g2a * 16 + l16)) * 320 + quad * 8;
    const ushort* wp1 = wbf + ((size_t)(g2b * 16 + l16)) * 320 + quad * 8;
#pragma unroll
    for (int s = 0; s < 10; ++s) { af0[s] = *(const bf16x8*)(wp0 + s * 32);
                                   af1[s] = *(const bf16x8*)(wp1 + s * 32); }
    float bi0 = bias[u0], bf0 = bias[256 + u0], bg0 = bias[512 + u0], bo0 = bias[768 + u0];
    float bi1 = bias[u1], bf1 = bias[256 + u1], bg1 = bias[512 + u1], bo1 = bias[768 + u1];
    float cs0 = 0.f, cs1 = 0.f;
    // xt preload for t=0 (B-frags shared by both M-tiles)
    const ushort* xpp = li + ((size_t)0 * 64 + bb) * 72 + quad * 8;
    bf16x8 x0 = *(const bf16x8*)xpp;
    bf16x8 x1 = *(const bf16x8*)(xpp + 32);
#pragma unroll 1
    for (int t = 0; t < TC_; ++t) {
        f32x4 A0 = {0.f, 0.f, 0.f, 0.f}, A1 = {0.f, 0.f, 0.f, 0.f};
        // x-part MFMAs first (xt already in regs from prefetch).
        A0 = __builtin_amdgcn_mfma_f32_16x16x32_bf16(af0[0], x0, A0, 0, 0, 0);
        A1 = __builtin_amdgcn_mfma_f32_16x16x32_bf16(af1[0], x0, A1, 0, 0, 0);
        A0 = __builtin_amdgcn_mfma_f32_16x16x32_bf16(af0[1], x1, A0, 0, 0, 0);
        A1 = __builtin_amdgcn_mfma_f32_16x16x32_bf16(af1[1], x1, A1, 0, 0, 0);
        if (t > 0) {
            uint tg = (uint)(t - 1);
            // Cache-bypass tagged poll+read: this thread's 4 cells of the pod image,
            // straight from MALL (sc0 sc1). waitcnt INSIDE the asm block.
            const u64* src = hbuf + ((size_t)((t - 1) & 1) << 13) + p * 2048 + tid * 4;
            u64 v0, v1, v2, v3;
            bool ok;
            int guard = 0;
            do {
                asm volatile(
                    "global_load_dwordx2 %0, %4, off sc0 sc1\n\t"
                    "global_load_dwordx2 %1, %4, off offset:8 sc0 sc1\n\t"
                    "global_load_dwordx2 %2, %4, off offset:16 sc0 sc1\n\t"
                    "global_load_dwordx2 %3, %4, off offset:24 sc0 sc1\n\t"
                    "s_waitcnt vmcnt(0)"
                    : "=&v"(v0), "=&v"(v1), "=&v"(v2), "=&v"(v3)
                    : "v"(src)
                    : "memory");
                uint m = (((uint)(v0 >> 16) & 0xFFFFu) ^ tg) | (((uint)(v0 >> 48)) ^ tg);
                m |= (((uint)(v1 >> 16) & 0xFFFFu) ^ tg) | (((uint)(v1 >> 48)) ^ tg);
                m |= (((uint)(v2 >> 16) & 0xFFFFu) ^ tg) | (((uint)(v2 >> 48)) ^ tg);
                m |= (((uint)(v3 >> 16) & 0xFFFFu) ^ tg) | (((uint)(v3 >> 48)) ^ tg);
                ok = (m == 0);
            } while (!__all(ok) && ++guard < (1 << 14));
            // Stage to LDS: idx=4*tid -> b=idx>>7, c=idx&127; cell c = units {2c,2c+1}.
            {
                int b = tid >> 5, c0 = (tid * 4) & 127;
                uint4 w;
                w.x = ((uint)v0 & 0xFFFFu) | (((uint)(v0 >> 32) & 0xFFFFu) << 16);
                w.y = ((uint)v1 & 0xFFFFu) | (((uint)(v1 >> 32) & 0xFFFFu) << 16);
                w.z = ((uint)v2 & 0xFFFFu) | (((uint)(v2 >> 32) & 0xFFFFu) << 16);
                w.w = ((uint)v3 & 0xFFFFu) | (((uint)(v3 >> 32) & 0xFFFFu) << 16);
                *(uint4*)((char*)Hs + b * 528 + c0 * 4) = w;
            }
            __syncthreads();
            // h-part MFMAs: frag = Hs[row=l16][units s*32+quad*8 ..+8], shared by both tiles.
#pragma unroll
            for (int s = 0; s < 8; ++s) {
                bf16x8 bh = *(const bf16x8*)((const char*)Hs + l16 * 528 + s * 64 + quad * 16);
                A0 = __builtin_amdgcn_mfma_f32_16x16x32_bf16(af0[2 + s], bh, A0, 0, 0, 0);
                A1 = __builtin_amdgcn_mfma_f32_16x16x32_bf16(af1[2 + s], bh, A1, 0, 0, 0);
            }
            __syncthreads();  // frag reads done before next step's staging overwrites Hs
        }
        // Epilogue: lane owns (u0,bb) and (u1,bb).
        float hv0, hv1;
        {
            float gi = A0[0] + bi0, gf = A0[1] + bf0, gg = A0[2] + bg0, go = A0[3] + bo0;
            float ii = sigmoidf_(gi), ff = sigmoidf_(gf), g2 = tanhf_(gg), oo = sigmoidf_(go);
            cs0 = ff * cs0 + ii * g2;
            hv0 = oo * tanhf_(cs0);
        }
        {
            float gi = A1[0] + bi1, gf = A1[1] + bf1, gg = A1[2] + bg1, go = A1[3] + bo1;
            float ii = sigmoidf_(gi), ff = sigmoidf_(gf), g2 = tanhf_(gg), oo = sigmoidf_(go);
            cs1 = ff * cs1 + ii * g2;
            hv1 = oo * tanhf_(cs1);
        }
        if (t == TC_ - 1) {
            hfin[u0 * 64 + bb] = hv0;
            hfin[u1 * 64 + bb] = hv1;
        } else {
            // Publish: pack unit pairs via shfl (quad gets quad+1's value, same l16).
            ushort h0 = f2bf(hv0), h1 = f2bf(hv1);
            uint pr0 = ((uint)h0 & 0xFFFFu) | ((uint)__shfl((int)h0, (lane + 16) & 63) << 16);
            uint pr1 = ((uint)h1 & 0xFFFFu) | ((uint)__shfl((int)h1, (lane + 16) & 63) << 16);
            if ((quad & 1) == 0) {
                uint tg2 = ((uint)t) << 16;
                u64 w0 = (u64)((pr0 & 0xFFFFu) | tg2) | ((u64)((pr0 >> 16) | tg2) << 32);
                u64 w1 = (u64)((pr1 & 0xFFFFu) | tg2) | ((u64)((pr1 >> 16) | tg2) << 32);
                int pc = 32 * q + 4 * wave + (quad >> 1);  // tile0 pair cell; tile1 = +2
                u64* dstp = hbuf + ((size_t)(t & 1) << 13) + p * 2048 + l16 * 128 + pc;
                // Cache-bypass write-through publish (fire-and-forget to MALL).
                asm volatile(
                    "global_store_dwordx2 %0, %1, off sc0 sc1\n\t"
                    "global_store_dwordx2 %0, %2, off offset:16 sc0 sc1"
                    :: "v"(dstp), "v"(w0), "v"(w1)
                    : "memory");
            }
        }
        // Prefetch next xt (fire after publish; lands during next poll).
        int tn = (t + 1 < TC_) ? t + 1 : t;
        const ushort* xpn = li + ((size_t)tn * 64 + bb) * 72 + quad * 8;
        x0 = *(const bf16x8*)xpn;
        x1 = *(const bf16x8*)(xpn + 32);
    }
    // Poison own cells in BOTH parities so next graph iteration's bypass loads never
    // see stale matching tags (0xFFFF is never a valid step).
    if ((quad & 1) == 0) {
        u64 poison = ~0ull;
        int pc = 32 * q + 4 * wave + (quad >> 1);
        u64* d0 = hbuf + p * 2048 + l16 * 128 + pc;
        u64* d1 = d0 + ((size_t)1 << 13);
        asm volatile(
            "global_store_dwordx2 %0, %2, off sc0 sc1\n\t"
            "global_store_dwordx2 %0, %2, off offset:16 sc0 sc1\n\t"
            "global_store_dwordx2 %1, %2, off sc0 sc1\n\t"
            "global_store_dwordx2 %1, %2, off offset:16 sc0 sc1\n\t"
            "s_waitcnt vmcnt(0)"
            :: "v"(d0), "v"(d1), "v"(poison)
            : "memory");
    }
}

// ---- Kernel 5: out[b][o] = h_final[:,b] . lin_w[o,:] + lin_b[o] ----
__global__ __launch_bounds__(64) void k_fin(const float* __restrict__ hfin, const float* __restrict__ lw,
                                            const float* __restrict__ lb, float* __restrict__ out) {
    int o = blockIdx.x, b = threadIdx.x;
    float acc = lb[o];
    const float* wp = lw + o * 256;
#pragma unroll 4
    for (int u2 = 0; u2 < 256; ++u2) acc += hfin[u2 * 64 + b] * wp[u2];
    out[b * 10 + o] = acc;
}

extern "C" void kernel_launch(void* const* d_in, const int* in_sizes, int n_in,
                              void* d_out, int out_size, void* d_ws, size_t ws_size,
                              hipStream_t stream) {
    const float* in  = (const float*)d_in[0];
    // d_in[1] ("r") unused
    const float* cw  = (const float*)d_in[2];
    const float* cb  = (const float*)d_in[3];
    const float* wih = (const float*)d_in[4];
    const float* whh = (const float*)d_in[5];
    const float* bih = (const float*)d_in[6];
    const float* bhh = (const float*)d_in[7];
    const float* lw  = (const float*)d_in[8];
    const float* lb  = (const float*)d_in[9];
    float* out = (float*)d_out;

    char* ws = (char*)d_ws;
    float*  sq   = (float*)(ws + 0);          // 32768 B
    u64*    hbuf = (u64*)(ws + 32768);        // 131072 B: 2 parity x (4 pods x 2048 cells) x 8B
    float*  bias = (float*)(ws + 163840);     // 4096 B
    float*  hfin = (float*)(ws + 167936);     // 65536 B  [u][b] fp32
    ushort* wbf  = (ushort*)(ws + 233472);    // 655360 B [g2][16][320] bf16
    ushort* li   = (ushort*)(ws + 888832);    // 9418752 B [tc][b][72] bf16

    hipMemsetAsync(sq, 0, 32768, stream);
    hipMemsetAsync(hbuf, 0xFF, 131072, stream);  // tag fields -> 0xFFFF, never a valid step

    k_sqsum<<<1024, 128, 0, stream>>>(in, sq);
    k_prep<<<1280, 256, 0, stream>>>(wih, whh, bih, bhh, wbf, bias);
    k_conv<<<2048, 256, 0, stream>>>(in, cw, cb, sq, li);
    k_scan<<<16, 512, 0, stream>>>(li, wbf, bias, hbuf, hfin);
    k_fin<<<10, 64, 0, stream>>>(hfin, lw, lb, out);
}